// Round 9
// baseline (184.140 us; speedup 1.0000x reference)
//
#include <hip/hip_runtime.h>
#include <hip/hip_bf16.h>
#include <math.h>

// Problem constants (reference: B=32, P=256, D=64, T=4096, SCALE=1)
#define Bb 32
#define Pp 256
#define Dd 64
#define Tt 4096

typedef unsigned short ushort_t;
typedef __attribute__((ext_vector_type(8))) short bf16x8;   // 8 bf16 = 4 VGPRs
typedef __attribute__((ext_vector_type(4))) float f32x4;

#define PRED_BYTES  ((size_t)Bb * Pp * Tt * sizeof(float))   // 134,217,728
#define SEG32_BYTES ((size_t)Bb * 32 * Tt * sizeof(float))   //  16,777,216
#define SEG16_BYTES ((size_t)Bb * 16 * Tt * sizeof(float))   //   8,388,608
#define A_BF_BYTES  ((size_t)Bb * Pp * Dd * 2)               //   1,048,576 (each)
#define B_BF_BYTES  ((size_t)Tt * Dd * 2)                    //     524,288 (each)
#define CONV_BYTES  (2 * A_BF_BYTES + 2 * B_BF_BYTES)        //   3,145,728

// ================== Phase 0: split-bf16 pre-conversion ======================
// x = hi(bf16,RNE) + lo(bf16); dropped al*bl term ~2^-17 rel -> pred err ~5e-4.
__global__ __launch_bounds__(256) void k_conv(const float* __restrict__ data,
                                              const float* __restrict__ task_pool,
                                              ushort_t* __restrict__ Ah, ushort_t* __restrict__ Al,
                                              ushort_t* __restrict__ Bh, ushort_t* __restrict__ Bl) {
  const int i  = blockIdx.x * 256 + threadIdx.x;
  const int NA = Bb * Pp * Dd;    // 524288
  const int NB = Tt * Dd;         // 262144
  if (i < NA) {
    const float x = data[i];
    __hip_bfloat16 h = __float2bfloat16(x);
    const float hf = __bfloat162float(h);
    __hip_bfloat16 l = __float2bfloat16(x - hf);
    Ah[i] = *(ushort_t*)&h; Al[i] = *(ushort_t*)&l;
  } else if (i < NA + NB) {
    const int j = i - NA;
    const float x = task_pool[j];
    __hip_bfloat16 h = __float2bfloat16(x);
    const float hf = __bfloat162float(h);
    __hip_bfloat16 l = __float2bfloat16(x - hf);
    Bh[j] = *(ushort_t*)&h; Bl[j] = *(ushort_t*)&l;
  }
}

// ===================== Phase 1: split-bf16 MFMA GEMM ========================
// R8 post-mortem: VALU k_gemm = 70 us with VALUBusy 49% ~= the 27 us fp32-FMA
// floor + epilogue + 8.4M LDS-conflict cycles + 2-blocks/CU occupancy. The
// fp32 vector path is the structural limit -> split-bf16 MFMA (3 terms:
// ah*bh + ah*bl + al*bh, fp32 acc). No LDS at all: frags are direct 16B
// loads from L2 (A 2MB, B 1MB, both cache-resident; ~160MB L2 traffic).
// Layouts (guide-verified, m89/m97/m120): A[m=lane&15][k=quad*8+j],
// B[n=lane&15][k=quad*8+j] (task_pool is [t][d] row-major = B^T, = m97 shape),
// C/D: col=lane&15, row=quad*4+reg.
// Block = 4 waves, tile 64m x 256n; wave = 16m x 256n strip. Grid 128x16.
// Epilogue: pred stores (fp32) + per-8p-segment score sums: lane's 4 acc rows
// all lie in one quad => quad q holds segment parity q&1... rows quad*4+reg:
// quads {0,1} = p 0..7 (seg sg0), quads {2,3} = p 8..15 (sg0+1); one
// shfl_xor(16) combines quad pairs. seg_sum[b][32][t] fp32 (exact anchors:
// scan's c-updates use the SAME pred values -> self-consistent prefixes).
__global__ __launch_bounds__(256, 4) void k_gemm2(const ushort_t* __restrict__ Ah,
                                                  const ushort_t* __restrict__ Al,
                                                  const ushort_t* __restrict__ Bh,
                                                  const ushort_t* __restrict__ Bl,
                                                  const float* __restrict__ targets,
                                                  float* __restrict__ C,
                                                  float* __restrict__ seg) {
  const int wid  = threadIdx.x >> 6;
  const int lane = threadIdx.x & 63;
  const int quad = lane >> 4;
  const int l16  = lane & 15;
  const int bm   = blockIdx.x * 64;    // 128 m-blocks (64 p-rows each)
  const int bn   = blockIdx.y * 256;   // 16 n-blocks
  const int ko   = quad * 8;

  // A fragments for this wave's 16 rows (k-chunks 0/1, hi/lo)
  const size_t arow = (size_t)(bm + wid * 16 + l16) * Dd;
  const bf16x8 ah0 = *(const bf16x8*)(Ah + arow + ko);
  const bf16x8 ah1 = *(const bf16x8*)(Ah + arow + 32 + ko);
  const bf16x8 al0 = *(const bf16x8*)(Al + arow + ko);
  const bf16x8 al1 = *(const bf16x8*)(Al + arow + 32 + ko);

  f32x4 acc[16];
#pragma unroll
  for (int nt = 0; nt < 16; ++nt) acc[nt] = (f32x4)0.f;

#pragma unroll
  for (int nt = 0; nt < 16; ++nt) {
    const size_t brow = (size_t)(bn + nt * 16 + l16) * Dd;
    const bf16x8 bh0 = *(const bf16x8*)(Bh + brow + ko);
    const bf16x8 bh1 = *(const bf16x8*)(Bh + brow + 32 + ko);
    const bf16x8 bl0 = *(const bf16x8*)(Bl + brow + ko);
    const bf16x8 bl1 = *(const bf16x8*)(Bl + brow + 32 + ko);
    f32x4 a = acc[nt];
    a = __builtin_amdgcn_mfma_f32_16x16x32_bf16(ah0, bh0, a, 0, 0, 0);
    a = __builtin_amdgcn_mfma_f32_16x16x32_bf16(ah1, bh1, a, 0, 0, 0);
    a = __builtin_amdgcn_mfma_f32_16x16x32_bf16(ah0, bl0, a, 0, 0, 0);
    a = __builtin_amdgcn_mfma_f32_16x16x32_bf16(al0, bh0, a, 0, 0, 0);
    a = __builtin_amdgcn_mfma_f32_16x16x32_bf16(ah1, bl1, a, 0, 0, 0);
    a = __builtin_amdgcn_mfma_f32_16x16x32_bf16(al1, bh1, a, 0, 0, 0);
    acc[nt] = a;
  }

  // ---- epilogue: pred stores + segment score sums
  const int prow  = bm + wid * 16 + quad * 4;       // global row of reg 0
  const int b     = bm >> 8;
  const int p_off = (bm & 255) + wid * 16;
  const int sg0   = p_off >> 3;                     // quads 0,1 -> sg0; 2,3 -> sg0+1
  float trr[4];
  *(float4*)trr = *(const float4*)(targets + prow);

#pragma unroll
  for (int nt = 0; nt < 16; ++nt) {
    const int t = bn + nt * 16 + l16;
    float sc = 0.f;
#pragma unroll
    for (int reg = 0; reg < 4; ++reg) {
      C[(size_t)(prow + reg) * Tt + t] = acc[nt][reg];
      const float e = trr[reg] - acc[nt][reg];
      sc = fmaf(-0.5f * e, e, sc);
    }
    sc += __shfl_xor(sc, 16, 64);
    if (quad == 0)      seg[(size_t)(b * 32 + sg0)     * Tt + t] = sc;
    else if (quad == 2) seg[(size_t)(b * 32 + sg0 + 1) * Tt + t] = sc;
  }
}

// ============ Fallback Phase 1: fp32 VALU GEMM (R8, proven) =================
__global__ __launch_bounds__(256, 2) void k_gemm(const float* __restrict__ A,
                                                 const float* __restrict__ Wt,
                                                 const float* __restrict__ targets,
                                                 float* __restrict__ C,
                                                 float* __restrict__ seg_sum,
                                                 int nseg) {
  __shared__ float As[Dd][128];
  __shared__ float Bs[Dd][128];
  const int tid = threadIdx.x;
  const int bm  = blockIdx.x * 128;
  const int bn  = blockIdx.y * 128;
  {
    const int k0 = (tid & 15) * 4;
    const int r0 = tid >> 4;
#pragma unroll
    for (int l = 0; l < 8; ++l) {
      const int r = r0 + l * 16;
      const float4 v = *(const float4*)(A + (size_t)(bm + r) * Dd + k0);
      As[k0 + 0][r] = v.x; As[k0 + 1][r] = v.y;
      As[k0 + 2][r] = v.z; As[k0 + 3][r] = v.w;
    }
  }
  {
    const int tt = tid >> 1;
    const int h  = (tid & 1) * 32;
    const float* src = Wt + (size_t)(bn + tt) * Dd + h;
#pragma unroll
    for (int i = 0; i < 8; ++i) {
      const float4 v = *(const float4*)(src + i * 4);
      const int k = h + i * 4;
      Bs[k + 0][tt] = v.x; Bs[k + 1][tt] = v.y;
      Bs[k + 2][tt] = v.z; Bs[k + 3][tt] = v.w;
    }
  }
  __syncthreads();
  const int tm8 = (tid >> 4) * 8;
  const int tn4 = (tid & 15) * 4;
  float acc[8][8];
#pragma unroll
  for (int i = 0; i < 8; ++i)
#pragma unroll
    for (int j = 0; j < 8; ++j) acc[i][j] = 0.f;
#pragma unroll 8
  for (int k = 0; k < Dd; ++k) {
    float a[8], bv[8];
    *(float4*)&a[0]  = *(const float4*)&As[k][tm8];
    *(float4*)&a[4]  = *(const float4*)&As[k][tm8 + 4];
    *(float4*)&bv[0] = *(const float4*)&Bs[k][tn4];
    *(float4*)&bv[4] = *(const float4*)&Bs[k][64 + tn4];
#pragma unroll
    for (int i = 0; i < 8; ++i)
#pragma unroll
      for (int j = 0; j < 8; ++j) acc[i][j] = fmaf(a[i], bv[j], acc[i][j]);
  }
#pragma unroll
  for (int i = 0; i < 8; ++i) {
    float* crow = C + (size_t)(bm + tm8 + i) * Tt + bn;
    *(float4*)(crow + tn4)      = make_float4(acc[i][0], acc[i][1], acc[i][2], acc[i][3]);
    *(float4*)(crow + 64 + tn4) = make_float4(acc[i][4], acc[i][5], acc[i][6], acc[i][7]);
  }
  float trow[8];
  *(float4*)&trow[0] = *(const float4*)(targets + bm + tm8);
  *(float4*)&trow[4] = *(const float4*)(targets + bm + tm8 + 4);
  float s8[8];
#pragma unroll
  for (int j = 0; j < 8; ++j) {
    float s = 0.f;
#pragma unroll
    for (int i = 0; i < 8; ++i) {
      const float e = trow[i] - acc[i][j];
      s = fmaf(-0.5f * e, e, s);
    }
    s8[j] = s;
  }
  const int grow = bm + tm8;
  const int b    = grow >> 8;
  if (nseg == 32) {
    const int sg = (grow >> 3) & 31;
    float* dst = seg_sum + ((size_t)(b * 32 + sg)) * Tt + bn;
    *(float4*)(dst + tn4)      = make_float4(s8[0], s8[1], s8[2], s8[3]);
    *(float4*)(dst + 64 + tn4) = make_float4(s8[4], s8[5], s8[6], s8[7]);
  } else {
#pragma unroll
    for (int j = 0; j < 8; ++j) s8[j] += __shfl_xor(s8[j], 16, 64);
    if (!(tid & 16)) {
      const int sg = (grow >> 4) & 15;
      float* dst = seg_sum + ((size_t)(b * 16 + sg)) * Tt + bn;
      *(float4*)(dst + tn4)      = make_float4(s8[0], s8[1], s8[2], s8[3]);
      *(float4*)(dst + 64 + tn4) = make_float4(s8[4], s8[5], s8[6], s8[7]);
    }
  }
}

// ================= Phase 2a: exclusive scan of segment sums =================
__global__ __launch_bounds__(256) void k_segscan(float* __restrict__ seg, int nseg) {
  const int gt = blockIdx.x * 256 + threadIdx.x;
  const int b  = gt >> 12;
  const int t  = gt & (Tt - 1);
  float* col = seg + (size_t)b * nseg * Tt + t;
  float run = 0.f;
  for (int s = 0; s < nseg; ++s) {
    const float v = col[(size_t)s * Tt];
    col[(size_t)s * Tt] = run;
    run += v;
  }
}

// ===================== Phase 2b: transposed scan (R8, proven) ===============
template <int NSEG>
__global__ __launch_bounds__(64, 1) void k_scan4(const float* __restrict__ pred,
                                                 const float* __restrict__ targets,
                                                 const float* __restrict__ segbase,
                                                 float* __restrict__ out) {
  constexpr int PSEG = Pp / NSEG;
  const int W    = blockIdx.x;
  const int b    = W / NSEG;
  const int seg  = W % NSEG;
  const int lane = threadIdx.x;

  float c[64];
  {
    const float* sb = segbase + (size_t)(b * NSEG + seg) * Tt + lane;
#pragma unroll
    for (int i = 0; i < 64; ++i) c[i] = sb[i * 64];
  }
  const float* __restrict__ pb = pred + (size_t)b * Pp * Tt + (size_t)(seg * PSEG) * Tt + lane;
  const float* __restrict__ tg = targets + b * Pp + seg * PSEG;
  float* __restrict__ ob       = out + b * Pp + seg * PSEG;

#pragma unroll 1
  for (int p = 0; p < PSEG; ++p) {
    float pr[64];
    {
      const float* pp = pb + (size_t)p * Tt;
#pragma unroll
      for (int i = 0; i < 64; ++i) pr[i] = pp[i * 64];
    }
    float mr[32];
#pragma unroll
    for (int i = 0; i < 32; ++i) mr[i] = fmaxf(c[i], c[i + 32]);
#pragma unroll
    for (int i = 0; i < 16; ++i) mr[i] = fmaxf(mr[i], mr[i + 16]);
#pragma unroll
    for (int i = 0; i < 8; ++i)  mr[i] = fmaxf(mr[i], mr[i + 8]);
#pragma unroll
    for (int i = 0; i < 4; ++i)  mr[i] = fmaxf(mr[i], mr[i + 4]);
    const float ml = fmaxf(fmaxf(mr[0], mr[2]), fmaxf(mr[1], mr[3]));

    float s = 0.f, v = 0.f;
#pragma unroll
    for (int i = 0; i < 64; ++i) {
      const float e = __expf(c[i] - ml);
      s += e;
      v = fmaf(e, pr[i], v);
    }
    const float tv = tg[p];
#pragma unroll
    for (int i = 0; i < 64; ++i) {
      const float err = tv - pr[i];
      c[i] = fmaf(-0.5f * err, err, c[i]);
    }
    float M = ml;
#pragma unroll
    for (int off = 32; off; off >>= 1) M = fmaxf(M, __shfl_xor(M, off, 64));
    const float f = __expf(ml - M);
    float S = f * s, V = f * v;
#pragma unroll
    for (int off = 32; off; off >>= 1) {
      S += __shfl_xor(S, off, 64);
      V += __shfl_xor(V, off, 64);
    }
    if (lane == 0) ob[p] = V / S;
  }
}

// ============== Fallback (tiny ws): fused R1 structure + merge ==============
__global__ __launch_bounds__(256) void k_scan_fused(const float* __restrict__ data,
                                                    const float* __restrict__ targets,
                                                    const float* __restrict__ task_pool,
                                                    float4* __restrict__ ws) {
  const int b     = blockIdx.x >> 4;
  const int wid   = threadIdx.x >> 6;
  const int lane  = threadIdx.x & 63;
  const int chunk = ((blockIdx.x & 15) << 2) | wid;
  const int t     = (chunk << 6) | lane;
  float w[Dd];
#pragma unroll
  for (int d = 0; d < Dd; d += 4) {
    const float4 r = *(const float4*)(task_pool + (size_t)t * Dd + d);
    w[d] = r.x; w[d + 1] = r.y; w[d + 2] = r.z; w[d + 3] = r.w;
  }
  const float* __restrict__ drow = data + (size_t)b * (Pp * Dd);
  const float* __restrict__ tgt  = targets + b * Pp;
  float4* __restrict__ wsb       = ws + (size_t)b * (Pp * 64);
  float c = 0.f;
  for (int p = 0; p < Pp; ++p) {
    float a0 = 0.f, a1 = 0.f, a2 = 0.f, a3 = 0.f;
    const float* __restrict__ r = drow + p * Dd;
#pragma unroll
    for (int d = 0; d < Dd; d += 4) {
      a0 = fmaf(r[d], w[d], a0);         a1 = fmaf(r[d + 1], w[d + 1], a1);
      a2 = fmaf(r[d + 2], w[d + 2], a2); a3 = fmaf(r[d + 3], w[d + 3], a3);
    }
    const float pred = (a0 + a1) + (a2 + a3);
    float m = c;
#pragma unroll
    for (int off = 32; off; off >>= 1) m = fmaxf(m, __shfl_xor(m, off, 64));
    const float e = __expf(c - m);
    float s = e, v = e * pred;
#pragma unroll
    for (int off = 32; off; off >>= 1) {
      s += __shfl_xor(s, off, 64);
      v += __shfl_xor(v, off, 64);
    }
    if (lane == 0) wsb[p * 64 + chunk] = make_float4(m, s, v, 0.f);
    const float err = tgt[p] - pred;
    c = fmaf(-0.5f * err, err, c);
  }
}

__global__ __launch_bounds__(256) void k_merge(const float4* __restrict__ ws,
                                               float* __restrict__ out) {
  const int gt   = blockIdx.x * 256 + threadIdx.x;
  const int bp   = gt >> 6;
  const int lane = gt & 63;
  const float4 o = ws[(size_t)bp * 64 + lane];
  const float m = o.x, s = o.y, v = o.z;
  float M = m;
#pragma unroll
  for (int off = 32; off; off >>= 1) M = fmaxf(M, __shfl_xor(M, off, 64));
  const float f = __expf(m - M);
  float S = f * s, V = f * v;
#pragma unroll
  for (int off = 32; off; off >>= 1) {
    S += __shfl_xor(S, off, 64);
    V += __shfl_xor(V, off, 64);
  }
  if (lane == 0) out[bp] = V / S;
}

extern "C" void kernel_launch(void* const* d_in, const int* in_sizes, int n_in,
                              void* d_out, int out_size, void* d_ws, size_t ws_size,
                              hipStream_t stream) {
  const float* data      = (const float*)d_in[0];
  const float* targets   = (const float*)d_in[1];
  const float* task_pool = (const float*)d_in[2];
  float* out = (float*)d_out;

  if (ws_size >= PRED_BYTES + SEG32_BYTES + CONV_BYTES) {
    float*    pred = (float*)d_ws;
    float*    seg  = (float*)((char*)d_ws + PRED_BYTES);
    char*     cb   = (char*)d_ws + PRED_BYTES + SEG32_BYTES;
    ushort_t* Ah   = (ushort_t*)cb;
    ushort_t* Al   = (ushort_t*)(cb + A_BF_BYTES);
    ushort_t* Bh   = (ushort_t*)(cb + 2 * A_BF_BYTES);
    ushort_t* Bl   = (ushort_t*)(cb + 2 * A_BF_BYTES + B_BF_BYTES);
    k_conv   <<<dim3(3072), dim3(256), 0, stream>>>(data, task_pool, Ah, Al, Bh, Bl);
    k_gemm2  <<<dim3(128, 16), dim3(256), 0, stream>>>(Ah, Al, Bh, Bl, targets, pred, seg);
    k_segscan<<<dim3(Bb * Tt / 256), dim3(256), 0, stream>>>(seg, 32);
    k_scan4<32><<<dim3(Bb * 32), dim3(64), 0, stream>>>(pred, targets, seg, out);
  } else if (ws_size >= PRED_BYTES + SEG32_BYTES) {
    float* pred = (float*)d_ws;
    float* seg  = (float*)((char*)d_ws + PRED_BYTES);
    k_gemm   <<<dim3(8192 / 128, Tt / 128), dim3(256), 0, stream>>>(data, task_pool, targets, pred, seg, 32);
    k_segscan<<<dim3(Bb * Tt / 256), dim3(256), 0, stream>>>(seg, 32);
    k_scan4<32><<<dim3(Bb * 32), dim3(64), 0, stream>>>(pred, targets, seg, out);
  } else if (ws_size >= PRED_BYTES + SEG16_BYTES) {
    float* pred = (float*)d_ws;
    float* seg  = (float*)((char*)d_ws + PRED_BYTES);
    k_gemm   <<<dim3(8192 / 128, Tt / 128), dim3(256), 0, stream>>>(data, task_pool, targets, pred, seg, 16);
    k_segscan<<<dim3(Bb * Tt / 256), dim3(256), 0, stream>>>(seg, 16);
    k_scan4<16><<<dim3(Bb * 16), dim3(64), 0, stream>>>(pred, targets, seg, out);
  } else {
    float4* triples = (float4*)d_ws;
    k_scan_fused<<<dim3(512), dim3(256), 0, stream>>>(data, targets, task_pool, triples);
    k_merge<<<dim3((Bb * Pp * 64) / 256), dim3(256), 0, stream>>>(triples, out);
  }
}

// Round 10
// 174.088 us; speedup vs baseline: 1.0577x; 1.0577x over previous
//
#include <hip/hip_runtime.h>
#include <hip/hip_bf16.h>
#include <math.h>

// Problem constants (reference: B=32, P=256, D=64, T=4096, SCALE=1)
#define Bb 32
#define Pp 256
#define Dd 64
#define Tt 4096

typedef __attribute__((ext_vector_type(8))) short bf16x8;   // 8 bf16 = 4 VGPRs
typedef __attribute__((ext_vector_type(4))) float f32x4;

#define PRED_BYTES  ((size_t)Bb * Pp * Tt * 4)   // 134,217,728
#define SEG32_BYTES ((size_t)Bb * 32 * Tt * 4)   //  16,777,216
#define SEG16_BYTES ((size_t)Bb * 16 * Tt * 4)   //   8,388,608

// x = hi(bf16,RNE) + lo(bf16): dropped al*bl term ~2^-17 rel; pred err ~5e-4.
__device__ __forceinline__ void split8(const float* __restrict__ x,
                                       bf16x8& hi, bf16x8& lo) {
#pragma unroll
  for (int j = 0; j < 8; ++j) {
    const __hip_bfloat16 hb = __float2bfloat16(x[j]);
    const float hf = __bfloat162float(hb);
    const __hip_bfloat16 lb = __float2bfloat16(x[j] - hf);
    hi[j] = *(const short*)&hb;
    lo[j] = *(const short*)&lb;
  }
}

// ================= Phase 1: split-bf16 MFMA GEMM, fixed stores ==============
// R9 post-mortem: MFMA gemm was write-DRAIN bound (all pipes <8%); its store
// insts covered only 4x64B segments. Fix: repack acc through LDS so each
// store inst is 8 rows x 128B = 1KB contiguous (R8-quality). Split-bf16
// conversion moved in-kernel (A once/wave, B per nt; VALU is free here —
// the kernel sits at the ~2.3 TB/s streaming-write wall).
// Epilogue also emits seg_sum[b][32][t] (8-p segments): per-lane over the 4
// quad rows + one shfl_xor(16)  (R9-proven).
__global__ __launch_bounds__(256, 3) void k_gemm3(const float* __restrict__ A,
                                                  const float* __restrict__ Wt,
                                                  const float* __restrict__ targets,
                                                  float* __restrict__ C,
                                                  float* __restrict__ seg) {
  __shared__ __align__(16) float ls[4][8][260];   // 33,280 B; pad 260 -> write-side 2-way max
  const int tid  = threadIdx.x;
  const int wid  = tid >> 6;
  const int lane = tid & 63;
  const int quad = lane >> 4;
  const int l16  = lane & 15;
  const int bm   = blockIdx.x * 64;    // 128 m-tiles (64 p-rows)
  const int bn   = blockIdx.y * 256;   // 16 n-tiles
  const int ko   = quad * 8;

  // A fragments for this wave's 16 rows (k-chunks 0/1, hi/lo), split on the fly
  bf16x8 ah0, al0, ah1, al1;
  {
    const float* ar = A + (size_t)(bm + wid * 16 + l16) * Dd;
    float a0[8], a1[8];
    *(float4*)&a0[0] = *(const float4*)(ar + ko);
    *(float4*)&a0[4] = *(const float4*)(ar + ko + 4);
    *(float4*)&a1[0] = *(const float4*)(ar + 32 + ko);
    *(float4*)&a1[4] = *(const float4*)(ar + 32 + ko + 4);
    split8(a0, ah0, al0);
    split8(a1, ah1, al1);
  }

  f32x4 acc[16];
#pragma unroll
  for (int nt = 0; nt < 16; ++nt) acc[nt] = (f32x4)0.f;

#pragma unroll
  for (int nt = 0; nt < 16; ++nt) {
    const float* br = Wt + (size_t)(bn + nt * 16 + l16) * Dd;
    float b0[8], b1[8];
    *(float4*)&b0[0] = *(const float4*)(br + ko);
    *(float4*)&b0[4] = *(const float4*)(br + ko + 4);
    *(float4*)&b1[0] = *(const float4*)(br + 32 + ko);
    *(float4*)&b1[4] = *(const float4*)(br + 32 + ko + 4);
    bf16x8 bh0, bl0, bh1, bl1;
    split8(b0, bh0, bl0);
    split8(b1, bh1, bl1);
    f32x4 a = acc[nt];
    a = __builtin_amdgcn_mfma_f32_16x16x32_bf16(ah0, bh0, a, 0, 0, 0);
    a = __builtin_amdgcn_mfma_f32_16x16x32_bf16(ah1, bh1, a, 0, 0, 0);
    a = __builtin_amdgcn_mfma_f32_16x16x32_bf16(ah0, bl0, a, 0, 0, 0);
    a = __builtin_amdgcn_mfma_f32_16x16x32_bf16(al0, bh0, a, 0, 0, 0);
    a = __builtin_amdgcn_mfma_f32_16x16x32_bf16(ah1, bl1, a, 0, 0, 0);
    a = __builtin_amdgcn_mfma_f32_16x16x32_bf16(al1, bh1, a, 0, 0, 0);
    acc[nt] = a;
  }

  // ---- seg sums (NSEG=32): lane's 4 acc rows are one quad; shfl_xor(16)
  // combines quad pairs (rows 0-7 -> quad0, rows 8-15 -> quad2).
  const int prow = bm + wid * 16 + quad * 4;
  const int b    = bm >> 8;
  const int sg0  = ((bm & 255) + wid * 16) >> 3;
  float trr[4];
  *(float4*)trr = *(const float4*)(targets + prow);
#pragma unroll
  for (int nt = 0; nt < 16; ++nt) {
    const int t = bn + nt * 16 + l16;
    float sc = 0.f;
#pragma unroll
    for (int reg = 0; reg < 4; ++reg) {
      const float e = trr[reg] - acc[nt][reg];
      sc = fmaf(-0.5f * e, e, sc);
    }
    sc += __shfl_xor(sc, 16, 64);
    if (quad == 0)      seg[(size_t)(b * 32 + sg0)     * Tt + t] = sc;
    else if (quad == 2) seg[(size_t)(b * 32 + sg0 + 1) * Tt + t] = sc;
  }

  // ---- pred stores via LDS repack: 2 passes of 8 rows; each store inst is
  // 8 rows x 128B contiguous (1KB/inst) instead of R9's 4x64B.
#pragma unroll
  for (int pass = 0; pass < 2; ++pass) {
    if ((quad >> 1) == pass) {
      const int lr = (quad & 1) * 4;   // local row base within the pass
#pragma unroll
      for (int nt = 0; nt < 16; ++nt)
#pragma unroll
        for (int reg = 0; reg < 4; ++reg)
          ls[wid][lr + reg][nt * 16 + l16] = acc[nt][reg];
    }
    __syncthreads();
    const int r = lane >> 3, j = lane & 7;   // 8 lanes per row
    float* crow = C + (size_t)(bm + wid * 16 + pass * 8 + r) * Tt + bn;
#pragma unroll
    for (int i = 0; i < 8; ++i) {
      const int t = i * 32 + j * 4;
      *(float4*)(crow + t) = *(const float4*)&ls[wid][r][t];
    }
    __syncthreads();
  }
}

// ================= Phase 2a: exclusive scan of segment sums =================
__global__ __launch_bounds__(256) void k_segscan(float* __restrict__ seg, int nseg) {
  const int gt = blockIdx.x * 256 + threadIdx.x;
  const int b  = gt >> 12;
  const int t  = gt & (Tt - 1);
  float* col = seg + (size_t)b * nseg * Tt + t;
  float run = 0.f;
  for (int s = 0; s < nseg; ++s) {
    const float v = col[(size_t)s * Tt];
    col[(size_t)s * Tt] = run;
    run += v;
  }
}

// ========================= Phase 2b: scan5 ==================================
// R9 budget analysis: scan4 ~= 50 us was pure latency exposure (1 wave/SIMD,
// 64 scalar loads/p). scan5: block = 4 waves per (b, 8-p seg), grid 1024 ->
// 4 waves/SIMD; lane owns 16 CONSECUTIVE t (t0 = wid*1024 + lane*16) so all
// loads are dwordx4 (4 insts/p); depth-1 prefetch of p+1; per-p cross-wave
// combine via 16B LDS + 1 barrier. Exact maxes at every level (R3: any
// non-exact shift underflows all lanes -> S=0 -> NaN): per-wave M is exact,
// max wave has f=1 so S>=1; block-level same.
__global__ __launch_bounds__(256, 4) void k_scan5(const float* __restrict__ pred,
                                                  const float* __restrict__ targets,
                                                  const float* __restrict__ segbase,
                                                  float* __restrict__ out) {
  __shared__ float4 part[2][4];
  const int tid  = threadIdx.x;
  const int wid  = tid >> 6;
  const int lane = tid & 63;
  const int blk  = blockIdx.x;        // b*32 + seg
  const int b    = blk >> 5;
  const int seg  = blk & 31;
  const int t0   = wid * 1024 + lane * 16;

  float c[16];
  {
    const float* sb = segbase + (size_t)blk * Tt + t0;
#pragma unroll
    for (int i = 0; i < 16; i += 4) *(float4*)&c[i] = *(const float4*)(sb + i);
  }
  const float* pb = pred + ((size_t)b * Pp + seg * 8) * Tt + t0;
  const float* tg = targets + b * Pp + seg * 8;
  float* ob       = out + b * Pp + seg * 8;

  float pr[2][16];
#pragma unroll
  for (int i = 0; i < 16; i += 4) *(float4*)&pr[0][i] = *(const float4*)(pb + i);

#pragma unroll
  for (int p = 0; p < 8; ++p) {
    const int cur = p & 1, nxt = cur ^ 1;
    if (p < 7) {     // prefetch next p's slice
      const float* q = pb + (size_t)(p + 1) * Tt;
#pragma unroll
      for (int i = 0; i < 16; i += 4) *(float4*)&pr[nxt][i] = *(const float4*)(q + i);
    }
    // per-lane tree max over c[16]
    float m8[8];
#pragma unroll
    for (int i = 0; i < 8; ++i) m8[i] = fmaxf(c[i], c[i + 8]);
#pragma unroll
    for (int i = 0; i < 4; ++i) m8[i] = fmaxf(m8[i], m8[i + 4]);
    const float ml = fmaxf(fmaxf(m8[0], m8[1]), fmaxf(m8[2], m8[3]));

    float s = 0.f, v = 0.f;
#pragma unroll
    for (int i = 0; i < 16; ++i) {
      const float e = __expf(c[i] - ml);
      s += e;
      v = fmaf(e, pr[cur][i], v);
    }
    const float tv = tg[p];
#pragma unroll
    for (int i = 0; i < 16; ++i) {
      const float err = tv - pr[cur][i];
      c[i] = fmaf(-0.5f * err, err, c[i]);
    }

    // wave reduce (exact max, then scaled sums)
    float M = ml;
#pragma unroll
    for (int off = 32; off; off >>= 1) M = fmaxf(M, __shfl_xor(M, off, 64));
    const float f = __expf(ml - M);
    float S = f * s, V = f * v;
#pragma unroll
    for (int off = 32; off; off >>= 1) {
      S += __shfl_xor(S, off, 64);
      V += __shfl_xor(V, off, 64);
    }
    if (lane == 0) part[cur][wid] = make_float4(M, S, V, 0.f);
    __syncthreads();
    if (tid == 0) {
      const float4 p0 = part[cur][0], p1 = part[cur][1],
                   p2 = part[cur][2], p3 = part[cur][3];
      const float MM = fmaxf(fmaxf(p0.x, p1.x), fmaxf(p2.x, p3.x));
      const float f0 = __expf(p0.x - MM), f1 = __expf(p1.x - MM);
      const float f2 = __expf(p2.x - MM), f3 = __expf(p3.x - MM);
      const float SS = f0 * p0.y + f1 * p1.y + f2 * p2.y + f3 * p3.y;
      const float VV = f0 * p0.z + f1 * p1.z + f2 * p2.z + f3 * p3.z;
      ob[p] = VV / SS;
    }
  }
}

// ============ Fallback Phase 1: fp32 VALU GEMM (R8, proven) =================
__global__ __launch_bounds__(256, 2) void k_gemm(const float* __restrict__ A,
                                                 const float* __restrict__ Wt,
                                                 const float* __restrict__ targets,
                                                 float* __restrict__ C,
                                                 float* __restrict__ seg_sum,
                                                 int nseg) {
  __shared__ float As[Dd][128];
  __shared__ float Bs[Dd][128];
  const int tid = threadIdx.x;
  const int bm  = blockIdx.x * 128;
  const int bn  = blockIdx.y * 128;
  {
    const int k0 = (tid & 15) * 4;
    const int r0 = tid >> 4;
#pragma unroll
    for (int l = 0; l < 8; ++l) {
      const int r = r0 + l * 16;
      const float4 v = *(const float4*)(A + (size_t)(bm + r) * Dd + k0);
      As[k0 + 0][r] = v.x; As[k0 + 1][r] = v.y;
      As[k0 + 2][r] = v.z; As[k0 + 3][r] = v.w;
    }
  }
  {
    const int tt = tid >> 1;
    const int h  = (tid & 1) * 32;
    const float* src = Wt + (size_t)(bn + tt) * Dd + h;
#pragma unroll
    for (int i = 0; i < 8; ++i) {
      const float4 v = *(const float4*)(src + i * 4);
      const int k = h + i * 4;
      Bs[k + 0][tt] = v.x; Bs[k + 1][tt] = v.y;
      Bs[k + 2][tt] = v.z; Bs[k + 3][tt] = v.w;
    }
  }
  __syncthreads();
  const int tm8 = (tid >> 4) * 8;
  const int tn4 = (tid & 15) * 4;
  float acc[8][8];
#pragma unroll
  for (int i = 0; i < 8; ++i)
#pragma unroll
    for (int j = 0; j < 8; ++j) acc[i][j] = 0.f;
#pragma unroll 8
  for (int k = 0; k < Dd; ++k) {
    float a[8], bv[8];
    *(float4*)&a[0]  = *(const float4*)&As[k][tm8];
    *(float4*)&a[4]  = *(const float4*)&As[k][tm8 + 4];
    *(float4*)&bv[0] = *(const float4*)&Bs[k][tn4];
    *(float4*)&bv[4] = *(const float4*)&Bs[k][64 + tn4];
#pragma unroll
    for (int i = 0; i < 8; ++i)
#pragma unroll
      for (int j = 0; j < 8; ++j) acc[i][j] = fmaf(a[i], bv[j], acc[i][j]);
  }
#pragma unroll
  for (int i = 0; i < 8; ++i) {
    float* crow = C + (size_t)(bm + tm8 + i) * Tt + bn;
    *(float4*)(crow + tn4)      = make_float4(acc[i][0], acc[i][1], acc[i][2], acc[i][3]);
    *(float4*)(crow + 64 + tn4) = make_float4(acc[i][4], acc[i][5], acc[i][6], acc[i][7]);
  }
  float trow[8];
  *(float4*)&trow[0] = *(const float4*)(targets + bm + tm8);
  *(float4*)&trow[4] = *(const float4*)(targets + bm + tm8 + 4);
  float s8[8];
#pragma unroll
  for (int j = 0; j < 8; ++j) {
    float s = 0.f;
#pragma unroll
    for (int i = 0; i < 8; ++i) {
      const float e = trow[i] - acc[i][j];
      s = fmaf(-0.5f * e, e, s);
    }
    s8[j] = s;
  }
  const int grow = bm + tm8;
  const int b    = grow >> 8;
#pragma unroll
  for (int j = 0; j < 8; ++j) s8[j] += __shfl_xor(s8[j], 16, 64);
  if (!(tid & 16)) {
    const int sg = (grow >> 4) & 15;
    float* dst = seg_sum + ((size_t)(b * 16 + sg)) * Tt + bn;
    *(float4*)(dst + tn4)      = make_float4(s8[0], s8[1], s8[2], s8[3]);
    *(float4*)(dst + 64 + tn4) = make_float4(s8[4], s8[5], s8[6], s8[7]);
  }
  (void)nseg;
}

// ================= Fallback Phase 2b: scan4<16> (R8, proven) ================
template <int NSEG>
__global__ __launch_bounds__(64, 1) void k_scan4(const float* __restrict__ pred,
                                                 const float* __restrict__ targets,
                                                 const float* __restrict__ segbase,
                                                 float* __restrict__ out) {
  constexpr int PSEG = Pp / NSEG;
  const int W    = blockIdx.x;
  const int b    = W / NSEG;
  const int seg  = W % NSEG;
  const int lane = threadIdx.x;
  float c[64];
  {
    const float* sb = segbase + (size_t)(b * NSEG + seg) * Tt + lane;
#pragma unroll
    for (int i = 0; i < 64; ++i) c[i] = sb[i * 64];
  }
  const float* pb = pred + (size_t)b * Pp * Tt + (size_t)(seg * PSEG) * Tt + lane;
  const float* tg = targets + b * Pp + seg * PSEG;
  float* ob       = out + b * Pp + seg * PSEG;
#pragma unroll 1
  for (int p = 0; p < PSEG; ++p) {
    float pr[64];
    {
      const float* pp = pb + (size_t)p * Tt;
#pragma unroll
      for (int i = 0; i < 64; ++i) pr[i] = pp[i * 64];
    }
    float mr[32];
#pragma unroll
    for (int i = 0; i < 32; ++i) mr[i] = fmaxf(c[i], c[i + 32]);
#pragma unroll
    for (int i = 0; i < 16; ++i) mr[i] = fmaxf(mr[i], mr[i + 16]);
#pragma unroll
    for (int i = 0; i < 8; ++i)  mr[i] = fmaxf(mr[i], mr[i + 8]);
#pragma unroll
    for (int i = 0; i < 4; ++i)  mr[i] = fmaxf(mr[i], mr[i + 4]);
    const float ml = fmaxf(fmaxf(mr[0], mr[2]), fmaxf(mr[1], mr[3]));
    float s = 0.f, v = 0.f;
#pragma unroll
    for (int i = 0; i < 64; ++i) {
      const float e = __expf(c[i] - ml);
      s += e;
      v = fmaf(e, pr[i], v);
    }
    const float tv = tg[p];
#pragma unroll
    for (int i = 0; i < 64; ++i) {
      const float err = tv - pr[i];
      c[i] = fmaf(-0.5f * err, err, c[i]);
    }
    float M = ml;
#pragma unroll
    for (int off = 32; off; off >>= 1) M = fmaxf(M, __shfl_xor(M, off, 64));
    const float f = __expf(ml - M);
    float S = f * s, V = f * v;
#pragma unroll
    for (int off = 32; off; off >>= 1) {
      S += __shfl_xor(S, off, 64);
      V += __shfl_xor(V, off, 64);
    }
    if (lane == 0) ob[p] = V / S;
  }
}

// ============== Fallback (tiny ws): fused R1 structure + merge ==============
__global__ __launch_bounds__(256) void k_scan_fused(const float* __restrict__ data,
                                                    const float* __restrict__ targets,
                                                    const float* __restrict__ task_pool,
                                                    float4* __restrict__ ws) {
  const int b     = blockIdx.x >> 4;
  const int wid   = threadIdx.x >> 6;
  const int lane  = threadIdx.x & 63;
  const int chunk = ((blockIdx.x & 15) << 2) | wid;
  const int t     = (chunk << 6) | lane;
  float w[Dd];
#pragma unroll
  for (int d = 0; d < Dd; d += 4) {
    const float4 r = *(const float4*)(task_pool + (size_t)t * Dd + d);
    w[d] = r.x; w[d + 1] = r.y; w[d + 2] = r.z; w[d + 3] = r.w;
  }
  const float* drow = data + (size_t)b * (Pp * Dd);
  const float* tgt  = targets + b * Pp;
  float4* wsb       = ws + (size_t)b * (Pp * 64);
  float c = 0.f;
  for (int p = 0; p < Pp; ++p) {
    float a0 = 0.f, a1 = 0.f, a2 = 0.f, a3 = 0.f;
    const float* r = drow + p * Dd;
#pragma unroll
    for (int d = 0; d < Dd; d += 4) {
      a0 = fmaf(r[d], w[d], a0);         a1 = fmaf(r[d + 1], w[d + 1], a1);
      a2 = fmaf(r[d + 2], w[d + 2], a2); a3 = fmaf(r[d + 3], w[d + 3], a3);
    }
    const float pred = (a0 + a1) + (a2 + a3);
    float m = c;
#pragma unroll
    for (int off = 32; off; off >>= 1) m = fmaxf(m, __shfl_xor(m, off, 64));
    const float e = __expf(c - m);
    float s = e, v = e * pred;
#pragma unroll
    for (int off = 32; off; off >>= 1) {
      s += __shfl_xor(s, off, 64);
      v += __shfl_xor(v, off, 64);
    }
    if (lane == 0) wsb[p * 64 + chunk] = make_float4(m, s, v, 0.f);
    const float err = tgt[p] - pred;
    c = fmaf(-0.5f * err, err, c);
  }
}

__global__ __launch_bounds__(256) void k_merge(const float4* __restrict__ ws,
                                               float* __restrict__ out) {
  const int gt   = blockIdx.x * 256 + threadIdx.x;
  const int bp   = gt >> 6;
  const int lane = gt & 63;
  const float4 o = ws[(size_t)bp * 64 + lane];
  const float m = o.x, s = o.y, v = o.z;
  float M = m;
#pragma unroll
  for (int off = 32; off; off >>= 1) M = fmaxf(M, __shfl_xor(M, off, 64));
  const float f = __expf(m - M);
  float S = f * s, V = f * v;
#pragma unroll
  for (int off = 32; off; off >>= 1) {
    S += __shfl_xor(S, off, 64);
    V += __shfl_xor(V, off, 64);
  }
  if (lane == 0) out[bp] = V / S;
}

extern "C" void kernel_launch(void* const* d_in, const int* in_sizes, int n_in,
                              void* d_out, int out_size, void* d_ws, size_t ws_size,
                              hipStream_t stream) {
  const float* data      = (const float*)d_in[0];
  const float* targets   = (const float*)d_in[1];
  const float* task_pool = (const float*)d_in[2];
  float* out = (float*)d_out;

  if (ws_size >= PRED_BYTES + SEG32_BYTES) {
    float* pred = (float*)d_ws;
    float* seg  = (float*)((char*)d_ws + PRED_BYTES);
    k_gemm3  <<<dim3(128, 16), dim3(256), 0, stream>>>(data, task_pool, targets, pred, seg);
    k_segscan<<<dim3(Bb * Tt / 256), dim3(256), 0, stream>>>(seg, 32);
    k_scan5  <<<dim3(Bb * 32), dim3(256), 0, stream>>>(pred, targets, seg, out);
  } else if (ws_size >= PRED_BYTES + SEG16_BYTES) {
    float* pred = (float*)d_ws;
    float* seg  = (float*)((char*)d_ws + PRED_BYTES);
    k_gemm   <<<dim3(8192 / 128, Tt / 128), dim3(256), 0, stream>>>(data, task_pool, targets, pred, seg, 16);
    k_segscan<<<dim3(Bb * Tt / 256), dim3(256), 0, stream>>>(seg, 16);
    k_scan4<16><<<dim3(Bb * 16), dim3(64), 0, stream>>>(pred, targets, seg, out);
  } else {
    float4* triples = (float4*)d_ws;   // 8.4 MB
    k_scan_fused<<<dim3(512), dim3(256), 0, stream>>>(data, targets, task_pool, triples);
    k_merge<<<dim3((Bb * Pp * 64) / 256), dim3(256), 0, stream>>>(triples, out);
  }
}